// Round 16
// baseline (180.959 us; speedup 1.0000x reference)
//
#include <hip/hip_runtime.h>

#define NN   10000
#define EE   160000
#define CINC 32
#define COUTC 32
#define RRR  6
#define MMM  3
#define RM   (RRR*MMM)      // 18
#define KK   (RM*CINC)      // 576
#define NPB  8              // nodes per block (one wave each)
#define CE   8              // edges staged per node per chunk
#define CAP  64             // fixed bucket capacity per node (mean degree 16)
#define AROW 592            // agg row stride in bf16 elems (576 + 16 pad)
#define SBS  40             // bf16 stencil row stride in shorts (36 valid + 4 pad = 80B)
#define EPSV 1e-8f

typedef __attribute__((ext_vector_type(8))) short bf16x8;
typedef __attribute__((ext_vector_type(4))) float f32x4;

__device__ inline short f2bf(float f) {            // round-to-nearest-even
    unsigned u = __float_as_uint(f);
    u = (u + 0x7FFF + ((u >> 16) & 1)) >> 16;
    return (short)u;
}
__device__ inline unsigned pk2(float re, float im) {
    return ((unsigned)(unsigned short)f2bf(im) << 16) |
            (unsigned)(unsigned short)f2bf(re);
}

// ---------------- build: bf16 weight planes + bucket-sorted bf16 stencil ----------------
// cursor[] pre-zeroed by hipMemsetAsync. The edge thread owns its bucket slot,
// so it converts its 144B stencil row to bf16 and writes it DIRECTLY into
// stenB[(tgt*CAP+pos)] — conv then reads the stencil with a pure induction
// address (contiguous 640B per chunk), no eid indirection anywhere.

__global__ void __launch_bounds__(256)
k_build(const int* __restrict__ edges, int* __restrict__ cursor,
        const float* __restrict__ w1, const float* __restrict__ off1,
        const float* __restrict__ w2, const float* __restrict__ off2,
        short* __restrict__ Wcb1, short* __restrict__ Wcb2,
        int* __restrict__ srcs,
        const float4* __restrict__ stenc4, short* __restrict__ stenB)
{
    int i = blockIdx.x*blockDim.x + threadIdx.x;
    if (i < KK*COUTC) {
        int d = i & 31;
        int k = i >> 5;                 // rm*32 + c
        int c = k & 31;
        float o1 = off1[c*COUTC + d];
        float o2 = off2[c*COUTC + d];
        float s1 = sinf(o1), c1 = cosf(o1);
        float s2 = sinf(o2), c2 = cosf(o2);
        Wcb1[d*KK + k]          = f2bf(w1[i]*c1);
        Wcb1[KK*COUTC + d*KK+k] = f2bf(w1[i]*s1);
        Wcb2[d*KK + k]          = f2bf(w2[i]*c2);
        Wcb2[KK*COUTC + d*KK+k] = f2bf(w2[i]*s2);
    }
    if (i < EE) {
        int src = edges[2*i];
        int tgt = edges[2*i+1];
        int pos = atomicAdd(&cursor[tgt], 1);
        if (pos < CAP) {
            srcs[tgt*CAP + pos] = src;
            const float4* s = stenc4 + (size_t)i * 9;
            unsigned w[20];
            #pragma unroll
            for (int j = 0; j < 9; ++j) {
                float4 v = s[j];
                w[2*j]   = pk2(v.x, v.y);
                w[2*j+1] = pk2(v.z, v.w);
            }
            w[18] = 0; w[19] = 0;
            uint4* drow = (uint4*)(stenB + ((size_t)tgt*CAP + pos)*SBS);
            #pragma unroll
            for (int k2 = 0; k2 < 5; ++k2)
                drow[k2] = make_uint4(w[4*k2], w[4*k2+1], w[4*k2+2], w[4*k2+3]);
        }
    }
}

// ---------------- fused conv: pipelined edge phase (bucket bf16 stencil) + MFMA einsum ----------------
// 8 nodes/block, 512 threads = 8 waves, 1 node/wave, natural node order
// (bucket layout makes the stencil stream globally sequential). Chunk staging:
// lanes 0..39 read ONE contiguous 640B block (pure induction address), expand
// bf16->fp32 during the LDS write; FMA loop identical to the fp32 version.
// x-row srcs broadcast via unconditional __shfl (EXEC-inactive source lanes
// return garbage — keep shfl full-wave). Einsum via mfma_f32_16x16x32_bf16,
// rm-split {3,3,2,2,2,2,2,2} over 8 waves.

template<bool FINAL>
__global__ void __launch_bounds__(512)
k_conv(const float2* __restrict__ xin,      // (NN,32) complex input
       const int*  __restrict__ cnts,       // (NN) per-node edge count
       const int*  __restrict__ srcs,       // (NN*CAP) src buckets
       const uint4* __restrict__ stenB4,    // (NN*CAP,5) uint4 bucket stencil rows
       const short* __restrict__ Wcb,       // [re|im][32][576] bf16
       const float* __restrict__ bias,      // (32)
       const float2* __restrict__ xres,     // (NN,32) original xc (FINAL)
       const float2* __restrict__ resw,     // (32,32) complex (FINAL)
       float2* __restrict__ out)            // (NN,32) complex
{
    __shared__ __align__(16) short aggS[2*NPB*AROW];     // 18944 B; later dump
    __shared__ __align__(16) float4 sten[NPB*2*CE*10];   // 20480 B dbuf (fp32 rows)
    int t = threadIdx.x;
    int g = t >> 6;                     // wave = node slot 0..7
    int l = t & 63;
    int n0 = blockIdx.x*NPB;

    // ---- edge aggregation (fp32 accumulate, pipelined) ----
    {
        int n = n0 + g;
        int c = l & 31;
        int h = l >> 5;                 // half: alternate edges
        int cnt = cnts[n]; if (cnt > CAP) cnt = CAP;
        int beg = n*CAP;
        int srcAll = 0;
        if (l < cnt) srcAll = srcs[beg + l];

        // LDS write slot: lane covers edge e0 = l/5, 16B part cp0 = l%5 (lanes 0..39)
        int e0 = l/5, cp0 = l - 5*e0;

        float4* bufA = sten + g*(2*CE*10);
        float4* bufB = bufA + CE*10;

        float2 acc[RM];
        #pragma unroll
        for (int k = 0; k < RM; ++k) acc[k] = make_float2(0.f, 0.f);

        int nchunks = (cnt + CE - 1) / CE;
        uint4 r0 = make_uint4(0,0,0,0);
        float2 xq[CE/2], xn[CE/2];

        auto stage_load = [&](int ck) {
            int ne = cnt - ck*CE; if (ne > CE) ne = CE;
            int nsl = ne*5;
            r0 = make_uint4(0,0,0,0);
            if (l < nsl) r0 = stenB4[((size_t)beg + ck*CE)*5 + l];   // contiguous
        };
        auto load_x = [&](int ck, float2* xr) {
            int ne = cnt - ck*CE; if (ne > CE) ne = CE;
            #pragma unroll
            for (int i = 0; i < CE/2; ++i) {
                int le = h + 2*i;
                int sl = ck*CE + le; if (sl > 63) sl = 63;
                int s = __shfl(srcAll, sl, 64);      // unconditional
                float2 v = make_float2(0.f, 0.f);
                if (le < ne) v = xin[(size_t)s*CINC + c];
                xr[i] = v;
            }
        };
        auto stage_write = [&](float4* dst, int ck) {
            int ne = cnt - ck*CE; if (ne > CE) ne = CE;
            int nsl = ne*5;
            if (l < nsl) {
                float4 fa = make_float4(__uint_as_float(r0.x << 16),
                                        __uint_as_float(r0.x & 0xFFFF0000u),
                                        __uint_as_float(r0.y << 16),
                                        __uint_as_float(r0.y & 0xFFFF0000u));
                float4 fb = make_float4(__uint_as_float(r0.z << 16),
                                        __uint_as_float(r0.z & 0xFFFF0000u),
                                        __uint_as_float(r0.w << 16),
                                        __uint_as_float(r0.w & 0xFFFF0000u));
                float4* p = dst + e0*10 + cp0*2;
                p[0] = fa;
                p[1] = fb;
            }
        };

        if (nchunks > 0) {
            stage_load(0); load_x(0, xq); stage_write(bufA, 0);
            for (int ck = 0; ck < nchunks; ++ck) {
                float4* cur = (ck & 1) ? bufB : bufA;
                float4* nxt = (ck & 1) ? bufA : bufB;
                bool more = (ck + 1 < nchunks);
                if (more) { stage_load(ck+1); load_x(ck+1, xn); }
                int ne = cnt - ck*CE; if (ne > CE) ne = CE;
                #pragma unroll
                for (int i = 0; i < CE/2; ++i) {
                    int le = h + 2*i;
                    if (le < ne) {
                        const float4* sp = cur + le*10;
                        float2 xv = xq[i];
                        #pragma unroll
                        for (int j = 0; j < 9; ++j) {
                            float4 s = sp[j];
                            acc[2*j].x   = fmaf(s.x, xv.x, fmaf(-s.y, xv.y, acc[2*j].x));
                            acc[2*j].y   = fmaf(s.x, xv.y, fmaf( s.y, xv.x, acc[2*j].y));
                            acc[2*j+1].x = fmaf(s.z, xv.x, fmaf(-s.w, xv.y, acc[2*j+1].x));
                            acc[2*j+1].y = fmaf(s.z, xv.y, fmaf( s.w, xv.x, acc[2*j+1].y));
                        }
                    }
                }
                if (more) {
                    stage_write(nxt, ck+1);
                    #pragma unroll
                    for (int i = 0; i < CE/2; ++i) xq[i] = xn[i];
                }
            }
        }

        #pragma unroll
        for (int k = 0; k < RM; ++k) {
            acc[k].x += __shfl_down(acc[k].x, 32, 64);
            acc[k].y += __shfl_down(acc[k].y, 32, 64);
        }
        if (h == 0) {                   // bf16 agg rows (deg==0 -> zeros)
            #pragma unroll
            for (int k = 0; k < RM; ++k) {
                aggS[g*AROW + k*32 + c]            = f2bf(acc[k].x);
                aggS[NPB*AROW + g*AROW + k*32 + c] = f2bf(acc[k].y);
            }
        }
    }
    __syncthreads();

    // ---- einsum via MFMA: D[m][d] = sum_k agg[m][k] * Wc[k][d] ----
    int quad = l >> 4;
    int nn16 = l & 15;
    int mrow = (nn16 < NPB) ? nn16 : NPB-1;       // rows >=8 ignored (dup of 7)
    int rm0 = (g < 2) ? 3*g : 2*g + 2;            // waves 0-1: 3 rm, else 2 rm
    int nrm = (g < 2) ? 3 : 2;
    const short* aggR = aggS;
    const short* aggI = aggS + NPB*AROW;
    const short* Wr = Wcb;
    const short* Wi = Wcb + KK*COUTC;

    f32x4 Prr[2], Pii[2], Pri[2], Pir[2];
    #pragma unroll
    for (int nt = 0; nt < 2; ++nt) {
        Prr[nt] = (f32x4)(0.f); Pii[nt] = (f32x4)(0.f);
        Pri[nt] = (f32x4)(0.f); Pir[nt] = (f32x4)(0.f);
    }
    for (int r = rm0; r < rm0 + nrm; ++r) {
        int koff = r*32 + quad*8;
        bf16x8 ar = *(const bf16x8*)(aggR + mrow*AROW + koff);
        bf16x8 ai = *(const bf16x8*)(aggI + mrow*AROW + koff);
        #pragma unroll
        for (int nt = 0; nt < 2; ++nt) {
            int d = nt*16 + nn16;
            bf16x8 br = *(const bf16x8*)(Wr + d*KK + koff);
            bf16x8 bi = *(const bf16x8*)(Wi + d*KK + koff);
            Prr[nt] = __builtin_amdgcn_mfma_f32_16x16x32_bf16(ar, br, Prr[nt], 0, 0, 0);
            Pii[nt] = __builtin_amdgcn_mfma_f32_16x16x32_bf16(ai, bi, Pii[nt], 0, 0, 0);
            Pri[nt] = __builtin_amdgcn_mfma_f32_16x16x32_bf16(ar, bi, Pri[nt], 0, 0, 0);
            Pir[nt] = __builtin_amdgcn_mfma_f32_16x16x32_bf16(ai, br, Pir[nt], 0, 0, 0);
        }
    }
    __syncthreads();                    // all agg reads done; reuse as dump

    // ---- dump partials: [wave][m][d] float2, rows m<8 only (quads 0,1) ----
    float2* dump = (float2*)aggS;       // 16384 B <= 18944
    if (quad < 2) {
        #pragma unroll
        for (int reg = 0; reg < 4; ++reg) {
            int m = quad*4 + reg;
            #pragma unroll
            for (int nt = 0; nt < 2; ++nt) {
                int d = nt*16 + nn16;
                dump[((size_t)g*NPB + m)*COUTC + d] =
                    make_float2(Prr[nt][reg] - Pii[nt][reg],
                                Pri[nt][reg] + Pir[nt][reg]);
            }
        }
    }
    __syncthreads();

    // ---- reduce 8 waves, residual, nonlinearity ----
    if (t < NPB*COUTC) {
        int m = t >> 5, d = t & 31;
        int n = n0 + m;
        float2 hv = make_float2(0.f, 0.f);
        #pragma unroll
        for (int w = 0; w < NPB; ++w) {
            float2 v = dump[((size_t)w*NPB + m)*COUTC + d];
            hv.x += v.x; hv.y += v.y;
        }
        if (FINAL) {
            const float2* xr = xres + (size_t)n * CINC;
            #pragma unroll
            for (int c = 0; c < CINC; ++c) {
                float2 xv = xr[c];
                float2 w = resw[c*COUTC + d];
                hv.x += xv.x*w.x - xv.y*w.y;
                hv.y += xv.x*w.y + xv.y*w.x;
            }
        }
        float mag = sqrtf(hv.x*hv.x + hv.y*hv.y);
        float num = mag + bias[d]; if (num < 0.f) num = 0.f;
        float den = (mag > EPSV) ? mag : EPSV;
        float f = num / den;
        out[(size_t)n*COUTC + d] = make_float2(f*hv.x, f*hv.y);
    }
}

// ---------------- launch ----------------

extern "C" void kernel_launch(void* const* d_in, const int* in_sizes, int n_in,
                              void* d_out, int out_size, void* d_ws, size_t ws_size,
                              hipStream_t stream) {
    const float2* xc   = (const float2*)d_in[0];   // (N,32,2) -> complex
    const int*   edges = (const int*)  d_in[1];    // (E,2)
    const float4* stenc4 = (const float4*)d_in[2]; // (E,6,3,2) -> (E,9) float4
    const float* w1    = (const float*)d_in[3];
    const float* off1  = (const float*)d_in[4];
    const float* b1    = (const float*)d_in[5];
    const float* w2    = (const float*)d_in[6];
    const float* off2  = (const float*)d_in[7];
    const float* b2    = (const float*)d_in[8];
    const float2* resw = (const float2*)d_in[9];   // (32,32) complex
    float2* out = (float2*)d_out;

    char* ws = (char*)d_ws;
    size_t o = 0;
    auto alloc = [&](size_t bytes) {
        o = (o + 255) & ~(size_t)255;
        size_t r = o; o += bytes; return r;
    };
    int*    cursor = (int*)  (ws + alloc(NN*sizeof(int)));
    int*    srcs   = (int*)  (ws + alloc((size_t)NN*CAP*sizeof(int)));
    short*  Wcb1   = (short*)(ws + alloc((size_t)2*KK*COUTC*sizeof(short)));
    short*  Wcb2   = (short*)(ws + alloc((size_t)2*KK*COUTC*sizeof(short)));
    short*  stenB  = (short*)(ws + alloc((size_t)NN*CAP*SBS*sizeof(short)));
    float2* h      = (float2*)(ws + alloc((size_t)NN*COUTC*sizeof(float2)));
    (void)ws_size; (void)in_sizes; (void)n_in; (void)out_size;

    hipMemsetAsync(cursor, 0, NN*sizeof(int), stream);
    k_build<<<(EE+255)/256, 256, 0, stream>>>(edges, cursor, w1, off1, w2, off2,
                                              Wcb1, Wcb2, srcs, stenc4, stenB);

    k_conv<false><<<NN/NPB, 512, 0, stream>>>(xc, cursor, srcs,
                                              (const uint4*)stenB, Wcb1, b1,
                                              nullptr, nullptr, h);
    k_conv<true> <<<NN/NPB, 512, 0, stream>>>(h, cursor, srcs,
                                              (const uint4*)stenB, Wcb2, b2,
                                              xc, resw, out);
}

// Round 17
// 180.356 us; speedup vs baseline: 1.0033x; 1.0033x over previous
//
#include <hip/hip_runtime.h>

#define NN   10000
#define EE   160000
#define CINC 32
#define COUTC 32
#define RRR  6
#define MMM  3
#define RM   (RRR*MMM)      // 18
#define KK   (RM*CINC)      // 576
#define NPB  8              // nodes per block (2 per wave, 4 waves, 256 threads)
#define CE   8              // edges per node per chunk
#define CAP  64             // fixed bucket capacity per node (mean degree 16)
#define AROW 592            // agg row stride in bf16 elems (576 + 16 pad)
#define SBS  40             // bf16 stencil row stride in shorts (36 valid + 4 pad = 80B)
#define EPSV 1e-8f

typedef __attribute__((ext_vector_type(8))) short bf16x8;
typedef __attribute__((ext_vector_type(4))) float f32x4;

__device__ inline short f2bf(float f) {            // round-to-nearest-even
    unsigned u = __float_as_uint(f);
    u = (u + 0x7FFF + ((u >> 16) & 1)) >> 16;
    return (short)u;
}
__device__ inline unsigned pk2(float re, float im) {
    return ((unsigned)(unsigned short)f2bf(im) << 16) |
            (unsigned)(unsigned short)f2bf(re);
}

// ---------------- build: bf16 weight planes + bucket-sorted bf16 stencil ----------------
// cursor[] pre-zeroed by hipMemsetAsync. Edge thread converts its 144B stencil
// row to bf16 and writes it directly into its bucket slot — conv reads the
// stencil with pure induction addresses, no eid indirection.

__global__ void __launch_bounds__(256)
k_build(const int* __restrict__ edges, int* __restrict__ cursor,
        const float* __restrict__ w1, const float* __restrict__ off1,
        const float* __restrict__ w2, const float* __restrict__ off2,
        short* __restrict__ Wcb1, short* __restrict__ Wcb2,
        int* __restrict__ srcs,
        const float4* __restrict__ stenc4, short* __restrict__ stenB)
{
    int i = blockIdx.x*blockDim.x + threadIdx.x;
    if (i < KK*COUTC) {
        int d = i & 31;
        int k = i >> 5;                 // rm*32 + c
        int c = k & 31;
        float o1 = off1[c*COUTC + d];
        float o2 = off2[c*COUTC + d];
        float s1 = sinf(o1), c1 = cosf(o1);
        float s2 = sinf(o2), c2 = cosf(o2);
        Wcb1[d*KK + k]          = f2bf(w1[i]*c1);
        Wcb1[KK*COUTC + d*KK+k] = f2bf(w1[i]*s1);
        Wcb2[d*KK + k]          = f2bf(w2[i]*c2);
        Wcb2[KK*COUTC + d*KK+k] = f2bf(w2[i]*s2);
    }
    if (i < EE) {
        int src = edges[2*i];
        int tgt = edges[2*i+1];
        int pos = atomicAdd(&cursor[tgt], 1);
        if (pos < CAP) {
            srcs[tgt*CAP + pos] = src;
            const float4* s = stenc4 + (size_t)i * 9;
            unsigned w[20];
            #pragma unroll
            for (int j = 0; j < 9; ++j) {
                float4 v = s[j];
                w[2*j]   = pk2(v.x, v.y);
                w[2*j+1] = pk2(v.z, v.w);
            }
            w[18] = 0; w[19] = 0;
            uint4* drow = (uint4*)(stenB + ((size_t)tgt*CAP + pos)*SBS);
            #pragma unroll
            for (int k2 = 0; k2 < 5; ++k2)
                drow[k2] = make_uint4(w[4*k2], w[4*k2+1], w[4*k2+2], w[4*k2+3]);
        }
    }
}

// ---------------- fused conv: 2 nodes/wave edge phase + bf16 MFMA einsum ----------------
// 256 threads = 4 waves x 2 nodes = 8 nodes/block -> 5000 waves total, all
// co-resident (5 blocks/CU by LDS ~31KB): single occupancy round, no tail.
// Each 32-lane half owns one node (c = l&31), processes its edges serially;
// stencil staged per chunk as bf16 into LDS (pipelined regs, unconditional
// stores, garbage rows predicated at compute), expanded bf16->fp32 in
// registers during the FMA. srcs staged per-wave in LDS (broadcast ds_read).
// No cross-half reduce. Einsum via mfma_f32_16x16x32_bf16, rm-split
// {5,5,4,4} over the 4 waves; cross-wave reduce via LDS dump.

template<bool FINAL>
__global__ void __launch_bounds__(256)
k_conv(const float2* __restrict__ xin,      // (NN,32) complex input
       const int*  __restrict__ cnts,       // (NN) per-node edge count
       const int*  __restrict__ srcs,       // (NN*CAP) src buckets
       const uint4* __restrict__ stenB4,    // (NN*CAP,5) uint4 bucket stencil rows
       const short* __restrict__ Wcb,       // [re|im][32][576] bf16
       const float* __restrict__ bias,      // (32)
       const float2* __restrict__ xres,     // (NN,32) original xc (FINAL)
       const float2* __restrict__ resw,     // (32,32) complex (FINAL)
       float2* __restrict__ out)            // (NN,32) complex
{
    __shared__ __align__(16) short aggS[2*NPB*AROW];   // 18944 B; later dump
    __shared__ __align__(16) uint4 stenL[4*2*80];      // 10240 B: 4 waves x 2 bufs x 80 slots
    __shared__ int srcL[4*128];                        // 2048 B: 4 waves x 2 nodes x 64
    int t = threadIdx.x;
    int g = t >> 6;                     // wave 0..3
    int l = t & 63;
    int n0 = blockIdx.x*NPB;

    // ---- edge aggregation (fp32 accumulate; half-wave per node) ----
    {
        int h = l >> 5, c = l & 31;
        int nA = n0 + 2*g, nB = nA + 1;
        int cntA = cnts[nA]; if (cntA > CAP) cntA = CAP;
        int cntB = cnts[nB]; if (cntB > CAP) cntB = CAP;
        int myCnt = h ? cntB : cntA;
        int begA = nA*CAP, begB = nB*CAP;

        int* mySrc = srcL + g*128;
        mySrc[l]      = srcs[begA + l];          // A slots 0..63 (garbage past cnt OK)
        mySrc[64 + l] = srcs[begB + l];          // B slots

        uint4* buf0 = stenL + g*160;
        uint4* buf1 = buf0 + 80;

        float2 acc[RM];
        #pragma unroll
        for (int k = 0; k < RM; ++k) acc[k] = make_float2(0.f, 0.f);

        int maxCnt = cntA > cntB ? cntA : cntB;
        int nch = (maxCnt + CE - 1) >> 3;

        uint4 r0 = make_uint4(0,0,0,0), r1 = r0;
        // slot map: A edge e -> slots e*5..e*5+4 (lanes 0..39);
        //           B edge e -> slots 40+e*5.. (lanes 40..63 = B slots 0..23,
        //           second load lanes 0..15 = B slots 24..39 -> LDS 64+l)
        auto stage_load = [&](int ck) {
            int rb  = (l < 40) ? (begA + ck*CE) : (begB + ck*CE);
            int off = (l < 40) ? l : (l - 40);
            r0 = stenB4[(size_t)rb*5 + off];                 // always in-bounds
            if (l < 16) r1 = stenB4[((size_t)begB + ck*CE)*5 + 24 + l];
        };
        auto stage_write = [&](uint4* dst) {
            dst[l] = r0;
            if (l < 16) dst[64 + l] = r1;
        };
        auto compute = [&](int ck, const uint4* cur) {
            int ne = myCnt - ck*CE; if (ne > CE) ne = CE;    // may be <=0
            float2 xv[CE];
            #pragma unroll
            for (int e = 0; e < CE; ++e) {
                int s = mySrc[h*64 + ck*CE + e];             // LDS broadcast
                float2 v = make_float2(0.f, 0.f);
                if (e < ne) v = xin[(size_t)s*CINC + c];
                xv[e] = v;
            }
            const uint4* rowb = cur + h*40;
            #pragma unroll
            for (int e = 0; e < CE; ++e) {
                if (e < ne) {
                    uint4 q0 = rowb[e*5+0], q1 = rowb[e*5+1], q2 = rowb[e*5+2],
                          q3 = rowb[e*5+3], q4 = rowb[e*5+4];
                    unsigned u[18] = {q0.x,q0.y,q0.z,q0.w, q1.x,q1.y,q1.z,q1.w,
                                      q2.x,q2.y,q2.z,q2.w, q3.x,q3.y,q3.z,q3.w,
                                      q4.x,q4.y};
                    float2 xvv = xv[e];
                    #pragma unroll
                    for (int j = 0; j < RM; ++j) {
                        float sr = __uint_as_float(u[j] << 16);
                        float si = __uint_as_float(u[j] & 0xFFFF0000u);
                        acc[j].x = fmaf(sr, xvv.x, fmaf(-si, xvv.y, acc[j].x));
                        acc[j].y = fmaf(sr, xvv.y, fmaf( si, xvv.x, acc[j].y));
                    }
                }
            }
        };

        if (nch > 0) {
            stage_load(0);
            stage_write(buf0);
            for (int ck = 0; ck < nch; ++ck) {
                uint4* cur = (ck & 1) ? buf1 : buf0;
                uint4* nxt = (ck & 1) ? buf0 : buf1;
                bool more = (ck + 1 < nch);
                if (more) stage_load(ck+1);
                compute(ck, cur);
                if (more) stage_write(nxt);
            }
        }

        int arow = 2*g + h;                 // my node's agg row
        #pragma unroll
        for (int k = 0; k < RM; ++k) {
            aggS[arow*AROW + k*32 + c]            = f2bf(acc[k].x);
            aggS[NPB*AROW + arow*AROW + k*32 + c] = f2bf(acc[k].y);
        }
    }
    __syncthreads();

    // ---- einsum via MFMA: D[m][d] = sum_k agg[m][k] * Wc[k][d] ----
    int quad = l >> 4;
    int nn16 = l & 15;
    int mrow = (nn16 < NPB) ? nn16 : NPB-1;       // A rows >=8 dup of 7 (ignored)
    int rm0 = (g < 2) ? 5*g : 4*g + 2;            // {0,5,10,14}
    int nrm = (g < 2) ? 5 : 4;
    const short* aggR = aggS;
    const short* aggI = aggS + NPB*AROW;
    const short* Wr = Wcb;
    const short* Wi = Wcb + KK*COUTC;

    f32x4 Prr[2], Pii[2], Pri[2], Pir[2];
    #pragma unroll
    for (int nt = 0; nt < 2; ++nt) {
        Prr[nt] = (f32x4)(0.f); Pii[nt] = (f32x4)(0.f);
        Pri[nt] = (f32x4)(0.f); Pir[nt] = (f32x4)(0.f);
    }
    for (int r = rm0; r < rm0 + nrm; ++r) {
        int koff = r*32 + quad*8;
        bf16x8 ar = *(const bf16x8*)(aggR + mrow*AROW + koff);
        bf16x8 ai = *(const bf16x8*)(aggI + mrow*AROW + koff);
        #pragma unroll
        for (int nt = 0; nt < 2; ++nt) {
            int d = nt*16 + nn16;
            bf16x8 br = *(const bf16x8*)(Wr + d*KK + koff);
            bf16x8 bi = *(const bf16x8*)(Wi + d*KK + koff);
            Prr[nt] = __builtin_amdgcn_mfma_f32_16x16x32_bf16(ar, br, Prr[nt], 0, 0, 0);
            Pii[nt] = __builtin_amdgcn_mfma_f32_16x16x32_bf16(ai, bi, Pii[nt], 0, 0, 0);
            Pri[nt] = __builtin_amdgcn_mfma_f32_16x16x32_bf16(ar, bi, Pri[nt], 0, 0, 0);
            Pir[nt] = __builtin_amdgcn_mfma_f32_16x16x32_bf16(ai, br, Pir[nt], 0, 0, 0);
        }
    }
    __syncthreads();                    // all agg reads done; reuse as dump

    // ---- dump partials: [wave][m][d] float2, rows m<8 only (quads 0,1) ----
    float2* dump = (float2*)aggS;       // 4*8*32*8 = 8192 B <= 18944
    if (quad < 2) {
        #pragma unroll
        for (int reg = 0; reg < 4; ++reg) {
            int m = quad*4 + reg;
            #pragma unroll
            for (int nt = 0; nt < 2; ++nt) {
                int d = nt*16 + nn16;
                dump[((size_t)g*NPB + m)*COUTC + d] =
                    make_float2(Prr[nt][reg] - Pii[nt][reg],
                                Pri[nt][reg] + Pir[nt][reg]);
            }
        }
    }
    __syncthreads();

    // ---- reduce 4 waves, residual, nonlinearity (all 256 threads) ----
    {
        int m = t >> 5, d = t & 31;
        int n = n0 + m;
        float2 hv = make_float2(0.f, 0.f);
        #pragma unroll
        for (int w = 0; w < 4; ++w) {
            float2 v = dump[((size_t)w*NPB + m)*COUTC + d];
            hv.x += v.x; hv.y += v.y;
        }
        if (FINAL) {
            const float2* xr = xres + (size_t)n * CINC;
            #pragma unroll
            for (int c = 0; c < CINC; ++c) {
                float2 xv = xr[c];
                float2 w = resw[c*COUTC + d];
                hv.x += xv.x*w.x - xv.y*w.y;
                hv.y += xv.x*w.y + xv.y*w.x;
            }
        }
        float mag = sqrtf(hv.x*hv.x + hv.y*hv.y);
        float num = mag + bias[d]; if (num < 0.f) num = 0.f;
        float den = (mag > EPSV) ? mag : EPSV;
        float f = num / den;
        out[(size_t)n*COUTC + d] = make_float2(f*hv.x, f*hv.y);
    }
}

// ---------------- launch ----------------

extern "C" void kernel_launch(void* const* d_in, const int* in_sizes, int n_in,
                              void* d_out, int out_size, void* d_ws, size_t ws_size,
                              hipStream_t stream) {
    const float2* xc   = (const float2*)d_in[0];   // (N,32,2) -> complex
    const int*   edges = (const int*)  d_in[1];    // (E,2)
    const float4* stenc4 = (const float4*)d_in[2]; // (E,6,3,2) -> (E,9) float4
    const float* w1    = (const float*)d_in[3];
    const float* off1  = (const float*)d_in[4];
    const float* b1    = (const float*)d_in[5];
    const float* w2    = (const float*)d_in[6];
    const float* off2  = (const float*)d_in[7];
    const float* b2    = (const float*)d_in[8];
    const float2* resw = (const float2*)d_in[9];   // (32,32) complex
    float2* out = (float2*)d_out;

    char* ws = (char*)d_ws;
    size_t o = 0;
    auto alloc = [&](size_t bytes) {
        o = (o + 255) & ~(size_t)255;
        size_t r = o; o += bytes; return r;
    };
    int*    cursor = (int*)  (ws + alloc(NN*sizeof(int)));
    int*    srcs   = (int*)  (ws + alloc((size_t)NN*CAP*sizeof(int)));
    short*  Wcb1   = (short*)(ws + alloc((size_t)2*KK*COUTC*sizeof(short)));
    short*  Wcb2   = (short*)(ws + alloc((size_t)2*KK*COUTC*sizeof(short)));
    short*  stenB  = (short*)(ws + alloc((size_t)NN*CAP*SBS*sizeof(short)));
    float2* h      = (float2*)(ws + alloc((size_t)NN*COUTC*sizeof(float2)));
    (void)ws_size; (void)in_sizes; (void)n_in; (void)out_size;

    hipMemsetAsync(cursor, 0, NN*sizeof(int), stream);
    k_build<<<(EE+255)/256, 256, 0, stream>>>(edges, cursor, w1, off1, w2, off2,
                                              Wcb1, Wcb2, srcs, stenc4, stenB);

    k_conv<false><<<NN/NPB, 256, 0, stream>>>(xc, cursor, srcs,
                                              (const uint4*)stenB, Wcb1, b1,
                                              nullptr, nullptr, h);
    k_conv<true> <<<NN/NPB, 256, 0, stream>>>(h, cursor, srcs,
                                              (const uint4*)stenB, Wcb2, b2,
                                              xc, resw, out);
}